// Round 6
// baseline (133.593 us; speedup 1.0000x reference)
//
#include <hip/hip_runtime.h>

// AttnMap restructure (verified rounds 1-5):
//   Mt[bt][f][ch] = sum_q dec[b, q*16+t, ch] * W[q*8 + (ch>>5)][f]
//   out[bt][s][f] = relu( sum_ch enc[bt][s][ch] * Mt[f][ch] + bias[f] )
// Round 6: B in LDS (XOR-swizzled, staged once, one barrier), 4 waves/block,
// 1024 blocks -> 16 waves/CU (4/SIMD). A-stream keeps the register
// double-buffer half-chunk pipeline. Goal: latency hiding via TLP.

#define CCH  256
#define FF   256
#define HW   1024

typedef __bf16 bf16x8 __attribute__((ext_vector_type(8)));
typedef float  f32x4  __attribute__((ext_vector_type(4)));
typedef unsigned short u16x8 __attribute__((ext_vector_type(8)));

__device__ __forceinline__ unsigned short f2bf(float f) {
    __bf16 b = (__bf16)f;
    return __builtin_bit_cast(unsigned short, b);
}

// ---------------- Phase 1: Mt[bt][f][ch] (bf16, f-major) ----------------
__global__ __launch_bounds__(256) void compute_Mt_kernel(
        const float* __restrict__ dec, const float* __restrict__ W,
        unsigned short* __restrict__ Mt) {
    const int j  = blockIdx.x;            // g-pair: g = 2j, 2j+1
    const int bt = blockIdx.y;
    const int b  = bt >> 4, t = bt & 15;
    const int f  = threadIdx.x;
    __shared__ float ldec[16][64];        // 16 q x 64 ch (this g-pair)

    const float* decbt = dec + (size_t)b * 65536 + (size_t)t * 256 + j * 64;
    {
        const int q = threadIdx.x >> 4, seg = threadIdx.x & 15;
        const float4 v = *reinterpret_cast<const float4*>(decbt + q * 4096 + seg * 4);
        *reinterpret_cast<float4*>(&ldec[q][seg * 4]) = v;
    }
    __syncthreads();

    u16x8 rv[8];
    #pragma unroll
    for (int gi = 0; gi < 2; ++gi) {
        const int g = j * 2 + gi;
        float wv[16];
        #pragma unroll
        for (int q = 0; q < 16; ++q) wv[q] = W[(q * 8 + g) * FF + f];   // coalesced
        #pragma unroll
        for (int cc = 0; cc < 32; ++cc) {
            float s = 0.f;
            #pragma unroll
            for (int q = 0; q < 16; ++q) s += ldec[q][gi * 32 + cc] * wv[q];
            const int idx = gi * 32 + cc;
            rv[idx >> 3][idx & 7] = f2bf(s);
        }
    }
    unsigned short* dst = Mt + (size_t)bt * (FF * CCH) + (size_t)f * CCH + j * 64;
    #pragma unroll
    for (int s = 0; s < 8; ++s)
        *reinterpret_cast<u16x8*>(dst + s * 8) = rv[s];   // 128 B/thread contiguous
}

// ---------------- Phase 2: streaming MFMA GEMM, B in swizzled LDS ----------------
// 1024 blocks x 256 thr (4 waves). Block = (bt, fq, rh): 512 rows x 64 f.
// Wave wq streams rows [rh*512 + wq*128, +128) in 8 chunks of 16.
// B frag (fn,kkg): LDS row = fn*16+lr, 16B-slot = (lg + kkg*4) ^ (lr&7).
__device__ __forceinline__ void loadA(const float* ap, f32x4* A) {
    #pragma unroll
    for (int kk = 0; kk < 4; ++kk) {
        A[2 * kk]     = *reinterpret_cast<const f32x4*>(ap + kk * 32);
        A[2 * kk + 1] = *reinterpret_cast<const f32x4*>(ap + kk * 32 + 4);
    }
}

__global__ __launch_bounds__(256, 4) void gemm_lds_kernel(
        const float* __restrict__ E, const unsigned short* __restrict__ Mt,
        const float* __restrict__ bias, float* __restrict__ O) {
    const int id0 = blockIdx.x;                       // 0..1023
    const int id  = ((id0 & 7) << 7) | (id0 >> 3);    // XCD-chunked bijection
    const int bt = id >> 3;
    const int fq = (id >> 1) & 3;                     // f quarter (64 f)
    const int rh = id & 1;                            // row half (512 rows)

    const float*          Ebt = E  + (size_t)bt * (HW * CCH);
    const unsigned short* Mtb = Mt + (size_t)bt * (FF * CCH) + (size_t)(fq * 64) * CCH;
    float*                Obt = O  + (size_t)bt * (HW * FF);

    __shared__ __align__(16) unsigned short Bs[64 * 256];   // 32 KB, swizzled 16B slots

    const int tid = threadIdx.x;
    // ---- stage B once: 2048 16B-slots, coalesced global, swizzled LDS ----
    #pragma unroll
    for (int p = 0; p < 8; ++p) {
        const int idx  = p * 256 + tid;           // 0..2047
        const int row  = idx >> 5;                // f-row 0..63
        const int slot = idx & 31;                // 16B slot in row
        const u16x8 v = *reinterpret_cast<const u16x8*>(Mtb + (size_t)row * CCH + slot * 8);
        *reinterpret_cast<u16x8*>(&Bs[row * 256 + (slot ^ (row & 7)) * 8]) = v;
    }
    __syncthreads();   // only barrier; waves free-run after this

    const int lane = tid & 63, wq = tid >> 6;
    const int lr = lane & 15;                     // row / f within 16
    const int lg = lane >> 4;                     // k-group 0..3
    const int sw = lr & 7;                        // lane's B-slot swizzle

    float bv[4];
    #pragma unroll
    for (int fn = 0; fn < 4; ++fn) bv[fn] = bias[fq * 64 + fn * 16 + lr];

    const int rowbase = rh * 512 + wq * 128;
    const float* abase = Ebt + (size_t)(rowbase + lr) * CCH + lg * 8;

    f32x4 A0[8], A1[8];                 // named half-buffers (static indexing only)
    loadA(abase, A0);                   // chunk 0, half 0

    for (int c = 0; c < 8; ++c) {
        const float* ap = abase + (size_t)c * 16 * CCH;
        loadA(ap + 128, A1);            // this chunk, half 1 (in flight over half-0 compute)
        f32x4 acc[4];
        #pragma unroll
        for (int fn = 0; fn < 4; ++fn) acc[fn] = (f32x4)0.f;

        #pragma unroll
        for (int kk = 0; kk < 4; ++kk) {          // half 0: kkg = kk
            bf16x8 a8;
            #pragma unroll
            for (int jj = 0; jj < 4; ++jj) {
                a8[jj]     = (__bf16)A0[2 * kk][jj];
                a8[4 + jj] = (__bf16)A0[2 * kk + 1][jj];
            }
            #pragma unroll
            for (int fn = 0; fn < 4; ++fn) {
                const bf16x8 bf = *reinterpret_cast<const bf16x8*>(
                    &Bs[(fn * 16 + lr) * 256 + (((lg + kk * 4) ^ sw)) * 8]);
                acc[fn] = __builtin_amdgcn_mfma_f32_16x16x32_bf16(a8, bf, acc[fn], 0, 0, 0);
            }
        }
        if (c < 7)
            loadA(ap + 16 * CCH, A0);   // next chunk, half 0 (in flight over half-1 compute)
        #pragma unroll
        for (int kk = 0; kk < 4; ++kk) {          // half 1: kkg = 4 + kk
            bf16x8 a8;
            #pragma unroll
            for (int jj = 0; jj < 4; ++jj) {
                a8[jj]     = (__bf16)A1[2 * kk][jj];
                a8[4 + jj] = (__bf16)A1[2 * kk + 1][jj];
            }
            #pragma unroll
            for (int fn = 0; fn < 4; ++fn) {
                const bf16x8 bf = *reinterpret_cast<const bf16x8*>(
                    &Bs[(fn * 16 + lr) * 256 + (((lg + (4 + kk) * 4) ^ sw)) * 8]);
                acc[fn] = __builtin_amdgcn_mfma_f32_16x16x32_bf16(a8, bf, acc[fn], 0, 0, 0);
            }
        }

        const int r0 = rowbase + c * 16;
        #pragma unroll
        for (int fn = 0; fn < 4; ++fn) {
            #pragma unroll
            for (int r = 0; r < 4; ++r) {
                const int row = r0 + lg * 4 + r;
                const float v = fmaxf(acc[fn][r] + bv[fn], 0.f);
                __builtin_nontemporal_store(
                    v, Obt + (size_t)row * FF + fq * 64 + fn * 16 + lr);
            }
        }
    }
}

extern "C" void kernel_launch(void* const* d_in, const int* in_sizes, int n_in,
                              void* d_out, int out_size, void* d_ws, size_t ws_size,
                              hipStream_t stream) {
    const float* dec  = (const float*)d_in[0];   // (8, 256, 256)
    const float* enc  = (const float*)d_in[1];   // (8, 16, 32, 32, 256)
    const float* W    = (const float*)d_in[2];   // (128, 256)
    const float* bias = (const float*)d_in[3];   // (256,)
    float* out = (float*)d_out;                  // (8, 16, 32, 32, 256) fp32
    unsigned short* Mt = (unsigned short*)d_ws;  // 128*256*256*2 = 16.8 MB bf16

    compute_Mt_kernel<<<dim3(4, 128), dim3(256), 0, stream>>>(dec, W, Mt);
    gemm_lds_kernel<<<dim3(1024), dim3(256), 0, stream>>>(enc, Mt, bias, out);
}

// Round 7
// 59.491 us; speedup vs baseline: 2.2456x; 2.2456x over previous
//
#include <hip/hip_runtime.h>

// AttnMap, fully fused (algebra verified rounds 1-6):
//   M[f][ch] = sum_q dec[b, q*16+t, ch] * W[q*8 + (ch>>5)][f]
//   out[bt][s][f] = relu( sum_ch enc[bt][s][ch] * M[f][ch] + bias[f] )
// One kernel. Block = (bt, fq, rh): 512 rows x 64 f. 4 waves, each 128 rows.
// Prologue computes the 64f x 256ch M-slice into shared LDS (bf16, swizzled).
// Main loop: coalesced full-line E loads -> reg cvt -> wave-private LDS tile
// -> ds_read_b128 frags -> mfma_32x32x16_bf16. No barriers in the main loop.
// LDS 40KB/block -> 4 blocks/CU = 16 waves/CU.

#define CCH 256
#define FF  256
#define HW  1024

typedef __bf16 bf16x8 __attribute__((ext_vector_type(8)));
typedef float  f32x4  __attribute__((ext_vector_type(4)));
typedef float  f32x16 __attribute__((ext_vector_type(16)));
typedef unsigned short u16x4 __attribute__((ext_vector_type(4)));
typedef unsigned short u16x8 __attribute__((ext_vector_type(8)));

__device__ __forceinline__ unsigned short f2bf(float f) {
    __bf16 b = (__bf16)f;
    return __builtin_bit_cast(unsigned short, b);
}

__global__ __launch_bounds__(256, 4) void attnmap_fused(
        const float* __restrict__ dec, const float* __restrict__ E,
        const float* __restrict__ W,  const float* __restrict__ bias,
        float* __restrict__ O) {
    const int id0 = blockIdx.x;                      // 0..1023
    const int id  = ((id0 & 7) << 7) | (id0 >> 3);   // XCD-chunked bijection
    const int bt = id >> 3;
    const int fq = (id >> 1) & 3;                    // 64-f slice
    const int rh = id & 1;                           // 512-row half
    const int tid = threadIdx.x;
    const int lane = tid & 63, wq = tid >> 6;
    const int lr5 = lane & 31, kgr = lane >> 5;

    __shared__ unsigned short Bs[64 * 256];          // 32 KB M-slice, bf16 swizzled
    __shared__ unsigned short Et[4][32 * 32];        // 4 x 2KB wave-private E tiles

    // ---------------- prologue: compute M[64f][256ch] into Bs ----------------
    {
        float* dstg = (float*)&Et[0][0];             // 2 KB staging [16 q][32 ch]
        const float* decb = dec + (size_t)(bt >> 4) * 65536 + (size_t)(bt & 15) * 256;
        const int fl = tid & 63, sc = tid >> 6;      // f-local, ch-subgroup
        for (int g = 0; g < 8; ++g) {
            if (tid < 128) {
                const int q = tid >> 3, seg = tid & 7;
                *reinterpret_cast<f32x4*>(&dstg[q * 32 + seg * 4]) =
                    *reinterpret_cast<const f32x4*>(decb + q * 4096 + g * 32 + seg * 4);
            }
            __syncthreads();
            float s[8];
            #pragma unroll
            for (int e = 0; e < 8; ++e) s[e] = 0.f;
            #pragma unroll
            for (int q = 0; q < 16; ++q) {
                const float w = W[(q * 8 + g) * FF + fq * 64 + fl];   // coalesced
                #pragma unroll
                for (int e = 0; e < 8; ++e) s[e] += dstg[q * 32 + sc * 8 + e] * w;
            }
            u16x8 m8;
            #pragma unroll
            for (int e = 0; e < 8; ++e) m8[e] = f2bf(s[e]);
            // row fl, 16B-slot (g*4+sc), XOR-swizzle with row&7 (matches read)
            *reinterpret_cast<u16x8*>(&Bs[fl * 256 + ((g * 4 + sc) ^ (fl & 7)) * 8]) = m8;
            __syncthreads();
        }
    }

    // ---------------- main loop: 128 rows/wave, 4 chunks x 8 k-steps ----------------
    const float* Ebt = E + (size_t)bt * (HW * CCH);
    float*       Obt = O + (size_t)bt * (HW * FF);
    const int rowbase = rh * 512 + wq * 128;
    unsigned short* Etw = &Et[wq][0];

    const float bv0 = bias[fq * 64 + lr5];
    const float bv1 = bias[fq * 64 + 32 + lr5];

    const int g_r8 = lane >> 3;                      // staging row-in-8
    const int g_s3 = lane & 7;                       // staging 16B slot
    const int bswz = lr5 & 7;                        // Bs read swizzle
    const int eswz = lr5 & 3;                        // E-tile read swizzle
    const unsigned short* Bs0 = &Bs[lr5 * 256];
    const unsigned short* Bs1 = &Bs[(32 + lr5) * 256];
    const unsigned short* Etr = &Etw[lr5 * 32];

    f32x4 Sva[4], Svb[4];
    f32x16 acc0, acc1;

    auto GLOAD = [&](int it, f32x4 (&S)[4]) {        // full 128B-line loads
        const float* base = Ebt + (size_t)(rowbase + (it >> 3) * 32) * CCH
                          + (it & 7) * 32 + g_s3 * 4;
        #pragma unroll
        for (int i = 0; i < 4; ++i)
            S[i] = *reinterpret_cast<const f32x4*>(base + (size_t)(i * 8 + g_r8) * CCH);
    };
    auto EWRITE = [&](const f32x4 (&S)[4]) {         // cvt + swizzled ds_write_b64
        #pragma unroll
        for (int i = 0; i < 4; ++i) {
            const int r = i * 8 + g_r8;
            u16x4 h = { f2bf(S[i][0]), f2bf(S[i][1]), f2bf(S[i][2]), f2bf(S[i][3]) };
            *reinterpret_cast<u16x4*>(
                &Etw[r * 32 + (((g_s3 >> 1) ^ (r & 3)) * 8) + (g_s3 & 1) * 4]) = h;
        }
    };
    auto COMPUTE = [&](int it) {
        const int kc = it & 7;
        if (kc == 0) { acc0 = (f32x16)0.f; acc1 = (f32x16)0.f; }
        #pragma unroll
        for (int kk = 0; kk < 2; ++kk) {
            const bf16x8 af = *reinterpret_cast<const bf16x8*>(
                &Etr[((kk * 2 + kgr) ^ eswz) * 8]);
            const bf16x8 b0 = *reinterpret_cast<const bf16x8*>(
                &Bs0[((kc * 4 + kk * 2 + kgr) ^ bswz) * 8]);
            const bf16x8 b1 = *reinterpret_cast<const bf16x8*>(
                &Bs1[((kc * 4 + kk * 2 + kgr) ^ bswz) * 8]);
            acc0 = __builtin_amdgcn_mfma_f32_32x32x16_bf16(af, b0, acc0, 0, 0, 0);
            acc1 = __builtin_amdgcn_mfma_f32_32x32x16_bf16(af, b1, acc1, 0, 0, 0);
        }
        if (kc == 7) {
            // C/D: col = lane&31, row = (reg&3) + 8*(reg>>2) + 4*(lane>>5)
            const int row0 = rowbase + (it >> 3) * 32 + 4 * kgr;
            #pragma unroll
            for (int reg = 0; reg < 16; ++reg) {
                const int r = row0 + (reg & 3) + 8 * (reg >> 2);
                float* op = Obt + (size_t)r * FF + fq * 64 + lr5;
                __builtin_nontemporal_store(fmaxf(acc0[reg] + bv0, 0.f), op);
                __builtin_nontemporal_store(fmaxf(acc1[reg] + bv1, 0.f), op + 32);
            }
        }
    };

    GLOAD(0, Sva);
    GLOAD(1, Svb);
    EWRITE(Sva);                      // tile <- it 0
    for (int itp = 0; itp < 32; itp += 2) {
        COMPUTE(itp);                 // reads tile(itp)
        if (itp + 2 < 32) GLOAD(itp + 2, Sva);
        EWRITE(Svb);                  // tile <- itp+1 (after reads of itp)
        COMPUTE(itp + 1);
        if (itp + 3 < 32) GLOAD(itp + 3, Svb);
        if (itp + 2 < 32) EWRITE(Sva);// tile <- itp+2
    }
}

extern "C" void kernel_launch(void* const* d_in, const int* in_sizes, int n_in,
                              void* d_out, int out_size, void* d_ws, size_t ws_size,
                              hipStream_t stream) {
    const float* dec  = (const float*)d_in[0];   // (8, 256, 256)
    const float* enc  = (const float*)d_in[1];   // (8, 16, 32, 32, 256)
    const float* W    = (const float*)d_in[2];   // (128, 256)
    const float* bias = (const float*)d_in[3];   // (256,)
    float* out = (float*)d_out;                  // (8, 16, 32, 32, 256) fp32

    attnmap_fused<<<dim3(1024), dim3(256), 0, stream>>>(dec, enc, W, bias, out);
}